// Round 18
// baseline (796.441 us; speedup 1.0000x reference)
//
#include <hip/hip_runtime.h>
#include <hip/hip_bf16.h>

#define TB 4
#define TN 640
#define TC 1024
#define TH 16
#define THD 64
#define TI 4096
#define TE 8
#define TT (TB*TN)     /* 2560 tokens */
#define TBH (TB*TH)    /* 64 */
#define SCALE_ 0.125f
#define NT1 32
#define NT2 48         /* cap: 128-row tiles across experts */

typedef unsigned short u16;
typedef __bf16 bf16x8 __attribute__((ext_vector_type(8)));
typedef float f32x4 __attribute__((ext_vector_type(4)));

__device__ __forceinline__ float gelu_tanh(float v){
  float t = 0.7978845608f*(v + 0.044715f*v*v*v);
  float e = __expf(2.f*t);
  return 0.5f*v*(1.f + (1.f - 2.f/(e + 1.f)));
}
__device__ __forceinline__ float b2f_(u16 u){
  union{float f;unsigned i;} v; v.i = (unsigned)u<<16; return v.f;
}

// ---------------------------------------------------------------------------
// 8-wave bf16 GEMM (r8/r12/r16-verified): static double buffers + one
// __syncthreads per K-step, STAGE-first. XOR-8 source+read swizzle.
// MODE 0: plain rows. MODE 1: tile-mapped gather (fc1). MODE 2: tile-mapped
// compact rows (fc2). EPI 1: bf16 (+bias if kc==0); EPI 3: gelu->bf16.
// ---------------------------------------------------------------------------
template<int BM,int BN,int MODE,int EPI>
__global__ __launch_bounds__(512) void gemm8(
    const u16* __restrict__ A, const u16* __restrict__ Wb, void* __restrict__ Cout,
    const float* __restrict__ bias, long biasStride,
    const int* __restrict__ tE, const int* __restrict__ tL,
    const int* __restrict__ tC, const int* __restrict__ tO,
    const int* __restrict__ etok,
    int M, int Kfull, int Kchunk, int n0, int ldc, long sW, long sCk)
{
  constexpr int FM = BM/32, FN = BN/64;
  constexpr int AI = BM/64, BI = BN/64;

  const int nwg = gridDim.x;
  int lin = blockIdx.x;
  int q = nwg >> 3, r = nwg & 7;
  int xcd = lin & 7, pos = lin >> 3;
  int swz = (xcd < r ? xcd*(q+1) : r*(q+1) + (xcd-r)*q) + pos;
  const int id0 = swz % n0, id1 = swz / n0;

  int e, loc0, cnt, off0, bx;
  if constexpr (MODE == 0){
    e = 0; loc0 = id0*BM; cnt = M; off0 = 0; bx = id1;
  } else {
    bx = id0;
    e = tE[id1]; if (e < 0) return;
    loc0 = tL[id1]; cnt = tC[id1]; off0 = tO[id1];
  }
  const int kc = blockIdx.z;
  const long kbase = (long)kc * Kchunk;

  const int tid = threadIdx.x, w = tid>>6, lane = tid&63;
  const int wm = w>>2, wn = w&3;

  __shared__ __align__(16) u16 As0[BM*64], As1[BM*64];
  __shared__ __align__(16) u16 Bs0[BN*64], Bs1[BN*64];

  const u16* Wz = Wb + (long)e*sW;

  const int c16 = (lane&7) ^ ((lane>>3)&7);
  long a_src[AI];
  #pragma unroll
  for (int j=0;j<AI;j++){
    int li = (w*AI+j)*8 + (lane>>3);
    int row;
    if constexpr (MODE == 0){
      row = loc0 + li;
    } else {
      int ll = loc0 + li; if (ll > cnt-1) ll = cnt-1;
      if constexpr (MODE == 1) row = etok[e*TT + ll];
      else                     row = off0 + ll;
    }
    a_src[j] = (long)row*Kfull + kbase + c16*8;
  }
  long b_src[BI];
  #pragma unroll
  for (int j=0;j<BI;j++){
    int rr = bx*BN + (w*BI+j)*8 + (lane>>3);
    b_src[j] = (long)rr*Kfull + kbase + c16*8;
  }

  auto STAGE = [&](u16 (&Ad)[BM*64], u16 (&Bd)[BN*64], int t){
    #pragma unroll
    for (int j=0;j<AI;j++)
      __builtin_amdgcn_global_load_lds(
        (const __attribute__((address_space(1))) void*)(A + a_src[j] + t*64),
        (__attribute__((address_space(3))) void*)(&Ad[(w*AI+j)*512]), 16, 0, 0);
    #pragma unroll
    for (int j=0;j<BI;j++)
      __builtin_amdgcn_global_load_lds(
        (const __attribute__((address_space(1))) void*)(Wz + b_src[j] + t*64),
        (__attribute__((address_space(3))) void*)(&Bd[(w*BI+j)*512]), 16, 0, 0);
  };

  f32x4 acc[FM][FN];
  #pragma unroll
  for (int m=0;m<FM;m++)
    #pragma unroll
    for (int n=0;n<FN;n++) acc[m][n] = (f32x4){0.f,0.f,0.f,0.f};

  const int lr = lane & 15;
  const int s0 = (lane>>4) ^ (lane&7);
  const int abase = lr*128 + s0*16;

  auto COMP = [&](const u16 (&As)[BM*64], const u16 (&Bs)[BN*64]){
    const char* Ab = (const char*)&As[0];
    const char* Bb = (const char*)&Bs[0];
    bf16x8 af[FM][2], bfr[FN][2];
    #pragma unroll
    for (int m=0;m<FM;m++){
      af[m][0] = *reinterpret_cast<const bf16x8*>(Ab + wm*(BM/2)*128 + m*2048 + abase);
      af[m][1] = *reinterpret_cast<const bf16x8*>(Ab + wm*(BM/2)*128 + m*2048 + (abase^64));
    }
    #pragma unroll
    for (int n=0;n<FN;n++){
      bfr[n][0] = *reinterpret_cast<const bf16x8*>(Bb + wn*(BN/4)*128 + n*2048 + abase);
      bfr[n][1] = *reinterpret_cast<const bf16x8*>(Bb + wn*(BN/4)*128 + n*2048 + (abase^64));
    }
    #pragma unroll
    for (int m=0;m<FM;m++)
      #pragma unroll
      for (int n=0;n<FN;n++){
        acc[m][n] = __builtin_amdgcn_mfma_f32_16x16x32_bf16(af[m][0], bfr[n][0], acc[m][n], 0,0,0);
        acc[m][n] = __builtin_amdgcn_mfma_f32_16x16x32_bf16(af[m][1], bfr[n][1], acc[m][n], 0,0,0);
      }
  };

  const int nt = Kchunk >> 6;
  STAGE(As0, Bs0, 0);
  __syncthreads();
  for (int t=0; t<nt; t+=2){
    if (t+1 < nt) STAGE(As1, Bs1, t+1);
    COMP(As0, Bs0);
    __syncthreads();
    if (t+1 < nt){
      if (t+2 < nt) STAGE(As0, Bs0, t+2);
      COMP(As1, Bs1);
      __syncthreads();
    }
  }

  const float* bz = (bias && kc==0) ? (bias + (long)e*biasStride) : nullptr;
  #pragma unroll
  for (int m=0;m<FM;m++){
    #pragma unroll
    for (int n=0;n<FN;n++){
      int gcol = bx*BN + wn*(BN/4) + n*16 + (lane&15);
      float bv = bz ? bz[gcol] : 0.f;
      #pragma unroll
      for (int jj=0;jj<4;jj++){
        int li = wm*(BM/2) + m*16 + (lane>>4)*4 + jj;
        int ll = loc0 + li;
        if (MODE != 0 && ll >= cnt) continue;
        float v = acc[m][n][jj] + bv;
        if constexpr (EPI == 3) v = gelu_tanh(v);
        long orow = (MODE == 0) ? (long)ll : (long)(off0 + ll);
        ((__hip_bfloat16*)Cout)[kc*sCk + orow*ldc + gcol] = __float2bfloat16(v);
      }
    }
  }
}

// ---------------------------------------------------------------------------
// 4-wave GEMM (proj), r8 structure.  EPI 2: resadd x += v*scalevec (RMW)
// ---------------------------------------------------------------------------
template<int BM,int BN,int EPI>
__global__ __launch_bounds__(256) void gemm_bt(
    const u16* __restrict__ A, const u16* __restrict__ Wb, void* __restrict__ Cout,
    const float* __restrict__ bias, const float* __restrict__ scalevec,
    int M, int Kfull, int nby, int ldc)
{
  constexpr int FM = BM/32, FN = BN/32;
  constexpr int AI = BM/32, BI = BN/32;

  const int nwg = gridDim.x;
  int lin = blockIdx.x;
  int q = nwg >> 3, r = nwg & 7;
  int xcd = lin & 7, pos = lin >> 3;
  int swz = (xcd < r ? xcd*(q+1) : r*(q+1) + (xcd-r)*q) + pos;
  const int bx = swz / nby;
  const int by = swz - bx*nby;
  if (by*BM >= M) return;

  const int tid = threadIdx.x, w = tid>>6, lane = tid&63;
  const int wm = w>>1, wn = w&1;

  __shared__ __align__(16) u16 As0[BM*64], As1[BM*64];
  __shared__ __align__(16) u16 Bs0[BN*64], Bs1[BN*64];

  const int c16 = (lane&7) ^ ((lane>>3)&7);
  long a_src[AI];
  #pragma unroll
  for (int j=0;j<AI;j++){
    int i = by*BM + (w*AI+j)*8 + (lane>>3);
    a_src[j] = (long)i*Kfull + c16*8;
  }
  long b_src[BI];
  #pragma unroll
  for (int j=0;j<BI;j++){
    int rr = bx*BN + (w*BI+j)*8 + (lane>>3);
    b_src[j] = (long)rr*Kfull + c16*8;
  }

  auto STAGE = [&](u16 (&Ad)[BM*64], u16 (&Bd)[BN*64], int t){
    #pragma unroll
    for (int j=0;j<AI;j++)
      __builtin_amdgcn_global_load_lds(
        (const __attribute__((address_space(1))) void*)(A + a_src[j] + t*64),
        (__attribute__((address_space(3))) void*)(&Ad[(w*AI+j)*512]), 16, 0, 0);
    #pragma unroll
    for (int j=0;j<BI;j++)
      __builtin_amdgcn_global_load_lds(
        (const __attribute__((address_space(1))) void*)(Wb + b_src[j] + t*64),
        (__attribute__((address_space(3))) void*)(&Bd[(w*BI+j)*512]), 16, 0, 0);
  };

  f32x4 acc[FM][FN];
  #pragma unroll
  for (int m=0;m<FM;m++)
    #pragma unroll
    for (int n=0;n<FN;n++) acc[m][n] = (f32x4){0.f,0.f,0.f,0.f};

  const int lr = lane & 15;
  const int s0 = (lane>>4) ^ (lane&7);
  const int abase = lr*128 + s0*16;

  auto COMP = [&](const u16 (&As)[BM*64], const u16 (&Bs)[BN*64]){
    const char* Ab = (const char*)&As[0];
    const char* Bb = (const char*)&Bs[0];
    bf16x8 af[FM][2], bfr[FN][2];
    #pragma unroll
    for (int m=0;m<FM;m++){
      af[m][0] = *reinterpret_cast<const bf16x8*>(Ab + wm*(BM/2)*128 + m*2048 + abase);
      af[m][1] = *reinterpret_cast<const bf16x8*>(Ab + wm*(BM/2)*128 + m*2048 + (abase^64));
    }
    #pragma unroll
    for (int n=0;n<FN;n++){
      bfr[n][0] = *reinterpret_cast<const bf16x8*>(Bb + wn*(BN/2)*128 + n*2048 + abase);
      bfr[n][1] = *reinterpret_cast<const bf16x8*>(Bb + wn*(BN/2)*128 + n*2048 + (abase^64));
    }
    #pragma unroll
    for (int m=0;m<FM;m++)
      #pragma unroll
      for (int n=0;n<FN;n++){
        acc[m][n] = __builtin_amdgcn_mfma_f32_16x16x32_bf16(af[m][0], bfr[n][0], acc[m][n], 0,0,0);
        acc[m][n] = __builtin_amdgcn_mfma_f32_16x16x32_bf16(af[m][1], bfr[n][1], acc[m][n], 0,0,0);
      }
  };

  const int nt = Kfull >> 6;
  STAGE(As0, Bs0, 0);
  __syncthreads();
  for (int t=0; t<nt; t+=2){
    if (t+1 < nt) STAGE(As1, Bs1, t+1);
    COMP(As0, Bs0);
    __syncthreads();
    if (t+1 < nt){
      if (t+2 < nt) STAGE(As0, Bs0, t+2);
      COMP(As1, Bs1);
      __syncthreads();
    }
  }

  #pragma unroll
  for (int m=0;m<FM;m++){
    #pragma unroll
    for (int n=0;n<FN;n++){
      int gcol = bx*BN + wn*(BN/2) + n*16 + (lane&15);
      float bv = bias ? bias[gcol] : 0.f;
      #pragma unroll
      for (int jj=0;jj<4;jj++){
        int i = by*BM + wm*(BM/2) + m*16 + (lane>>4)*4 + jj;
        float v = acc[m][n][jj] + bv;
        float* p = (float*)Cout + (long)i*ldc + gcol;
        *p += v * scalevec[gcol];
      }
    }
  }
}

// ---------------------------------------------------------------------------
// Fused flash attention, 64-row Q-tiles (r17-verified): per block (bh, qt),
// 4 waves x 16 q-rows. Q/K direct from qkv_bf; V^T from vT; rpb bf16.
// ---------------------------------------------------------------------------
__global__ __launch_bounds__(256) void fattn(
    const u16* __restrict__ qkv, const u16* __restrict__ vT,
    const u16* __restrict__ rpb16, const int* __restrict__ mask, u16* __restrict__ attn_o)
{
  const int blk = blockIdx.x;
  const int bh = blk / 10, qt = blk - bh*10;
  const int b = bh >> 4, h = bh & 15;
  const int q0 = qt * 64;
  const int tid = threadIdx.x, w = tid >> 6, lane = tid & 63;

  __shared__ __align__(16) u16 Qs[64*64];
  __shared__ __align__(16) u16 Ks0[64*64], Ks1[64*64];
  __shared__ __align__(16) u16 Vs0[64*64], Vs1[64*64];
  __shared__ __align__(16) u16 Ps[4][16*72];

  const int c16 = (lane&7) ^ ((lane>>3)&7);
  const long qkbase = (long)h*THD;
  #pragma unroll
  for (int j=0;j<2;j++){
    int row = (w*2+j)*8 + (lane>>3);
    __builtin_amdgcn_global_load_lds(
      (const __attribute__((address_space(1))) void*)(qkv + (long)(b*TN + q0 + row)*(3*TC) + qkbase + c16*8),
      (__attribute__((address_space(3))) void*)(&Qs[(w*2+j)*512]), 16, 0, 0);
  }

  auto STAGE = [&](u16 (&Kd)[64*64], u16 (&Vd)[64*64], int k0){
    #pragma unroll
    for (int j=0;j<2;j++){
      int row = (w*2+j)*8 + (lane>>3);
      __builtin_amdgcn_global_load_lds(
        (const __attribute__((address_space(1))) void*)(qkv + (long)(b*TN + k0 + row)*(3*TC) + TC + qkbase + c16*8),
        (__attribute__((address_space(3))) void*)(&Kd[(w*2+j)*512]), 16, 0, 0);
      __builtin_amdgcn_global_load_lds(
        (const __attribute__((address_space(1))) void*)(vT + ((long)bh*THD + row)*TN + k0 + c16*8),
        (__attribute__((address_space(3))) void*)(&Vd[(w*2+j)*512]), 16, 0, 0);
    }
  };

  const int s0 = (lane>>4) ^ (lane&7);
  const int lr = lane & 15;

  f32x4 acc_o[4];
  #pragma unroll
  for (int nd=0;nd<4;nd++) acc_o[nd] = (f32x4){0.f,0.f,0.f,0.f};
  float m_r[4], l_r[4];
  #pragma unroll
  for (int jj=0;jj<4;jj++){ m_r[jj] = -3e38f; l_r[jj] = 0.f; }

  auto TILE = [&](const u16 (&Ks)[64*64], const u16 (&Vs)[64*64], int k0){
    const char* Qb = (const char*)&Qs[0];
    const char* Kb = (const char*)&Ks[0];
    const char* Vb = (const char*)&Vs[0];
    bf16x8 qa[2], kf[4][2];
    {
      int row = w*16 + lr;
      qa[0] = *reinterpret_cast<const bf16x8*>(Qb + row*128 + s0*16);
      qa[1] = *reinterpret_cast<const bf16x8*>(Qb + row*128 + (s0*16^64));
    }
    #pragma unroll
    for (int nk=0;nk<4;nk++){
      int row = nk*16 + lr;
      kf[nk][0] = *reinterpret_cast<const bf16x8*>(Kb + row*128 + s0*16);
      kf[nk][1] = *reinterpret_cast<const bf16x8*>(Kb + row*128 + (s0*16^64));
    }
    f32x4 acc_s[4];
    #pragma unroll
    for (int nk=0;nk<4;nk++){
      acc_s[nk] = (f32x4){0.f,0.f,0.f,0.f};
      acc_s[nk] = __builtin_amdgcn_mfma_f32_16x16x32_bf16(qa[0], kf[nk][0], acc_s[nk], 0,0,0);
      acc_s[nk] = __builtin_amdgcn_mfma_f32_16x16x32_bf16(qa[1], kf[nk][1], acc_s[nk], 0,0,0);
    }
    float sc[4];
    #pragma unroll
    for (int jj=0;jj<4;jj++){
      int qrow = q0 + w*16 + (lane>>4)*4 + jj;
      float s[4];
      #pragma unroll
      for (int nk=0;nk<4;nk++){
        int kg = k0 + nk*16 + lr;
        float t = acc_s[nk][jj]*SCALE_ + b2f_(rpb16[((long)h*TN + qrow)*TN + kg]);
        if (mask[b*TN + kg] == 0) t = -1e30f;
        s[nk] = t;
      }
      float mx = fmaxf(fmaxf(s[0],s[1]), fmaxf(s[2],s[3]));
      #pragma unroll
      for (int o=1;o<16;o<<=1) mx = fmaxf(mx, __shfl_xor(mx, o));
      float mnew = fmaxf(m_r[jj], mx);
      float scale = __expf(m_r[jj] - mnew);
      float rs = 0.f;
      #pragma unroll
      for (int nk=0;nk<4;nk++){ s[nk] = __expf(s[nk] - mnew); rs += s[nk]; }
      #pragma unroll
      for (int o=1;o<16;o<<=1) rs += __shfl_xor(rs, o);
      l_r[jj] = l_r[jj]*scale + rs;
      m_r[jj] = mnew;
      sc[jj] = scale;
      int qloc = (lane>>4)*4 + jj;
      #pragma unroll
      for (int nk=0;nk<4;nk++)
        Ps[w][qloc*72 + nk*16 + lr] = (u16)__bfloat16_as_ushort(__float2bfloat16(s[nk]));
    }
    f32x4 sv = (f32x4){sc[0], sc[1], sc[2], sc[3]};
    #pragma unroll
    for (int nd=0;nd<4;nd++) acc_o[nd] *= sv;

    const char* Pw = (const char*)&Ps[w][0];
    bf16x8 pa[2], vb[4][2];
    {
      int qloc = lr;
      pa[0] = *reinterpret_cast<const bf16x8*>(Pw + qloc*144 + (lane>>4)*16);
      pa[1] = *reinterpret_cast<const bf16x8*>(Pw + qloc*144 + (lane>>4)*16 + 64);
    }
    #pragma unroll
    for (int nd=0;nd<4;nd++){
      int row = nd*16 + lr;
      vb[nd][0] = *reinterpret_cast<const bf16x8*>(Vb + row*128 + s0*16);
      vb[nd][1] = *reinterpret_cast<const bf16x8*>(Vb + row*128 + (s0*16^64));
    }
    #pragma unroll
    for (int nd=0;nd<4;nd++){
      acc_o[nd] = __builtin_amdgcn_mfma_f32_16x16x32_bf16(pa[0], vb[nd][0], acc_o[nd], 0,0,0);
      acc_o[nd] = __builtin_amdgcn_mfma_f32_16x16x32_bf16(pa[1], vb[nd][1], acc_o[nd], 0,0,0);
    }
  };

  STAGE(Ks0, Vs0, 0);
  __syncthreads();
  for (int t=0; t<10; t+=2){
    if (t+1 < 10) STAGE(Ks1, Vs1, (t+1)*64);
    TILE(Ks0, Vs0, t*64);
    __syncthreads();
    if (t+1 < 10){
      if (t+2 < 10) STAGE(Ks0, Vs0, (t+2)*64);
      TILE(Ks1, Vs1, (t+1)*64);
      __syncthreads();
    }
  }

  {
    float linv[4];
    #pragma unroll
    for (int jj=0;jj<4;jj++) linv[jj] = 1.f / l_r[jj];
    #pragma unroll
    for (int nd=0;nd<4;nd++){
      #pragma unroll
      for (int jj=0;jj<4;jj++){
        int qg = q0 + w*16 + (lane>>4)*4 + jj;
        int dg = h*THD + nd*16 + lr;
        attn_o[(long)(b*TN + qg)*TC + dg] =
          (u16)__bfloat16_as_ushort(__float2bfloat16(acc_o[nd][jj]*linv[jj]));
      }
    }
  }
}

// grid (5, TBH): LDS-transpose v section of qkv_bf into vT[bh][d][n]
__global__ __launch_bounds__(256) void v_transpose(const u16* __restrict__ qkv,
    u16* __restrict__ vT)
{
  const int bh = blockIdx.y, b = bh>>4, h = bh&15;
  const int n0 = blockIdx.x*128;
  const int tid = threadIdx.x;
  __shared__ u16 vt[128][72];
  #pragma unroll
  for (int j=0;j<4;j++){
    int f = j*2048 + tid*8;
    int r = f>>6, d = f&63;
    *(uint4*)(&vt[r][d]) = *(const uint4*)(qkv + (long)(b*TN + n0 + r)*(3*TC) + 2*TC + h*THD + d);
  }
  __syncthreads();
  #pragma unroll
  for (int j=0;j<4;j++){
    int f = j*2048 + tid*8;
    int dr = f>>7, nc = f&127;
    union { uint4 v; u16 u[8]; } o;
    #pragma unroll
    for (int e=0;e<8;e++) o.u[e] = vt[nc+e][dr];
    *(uint4*)(vT + ((long)bh*THD + dr)*TN + n0 + nc) = o.v;
  }
}

// ---------------------------------------------------------------------------
__global__ __launch_bounds__(256) void cvt_kernel(const float* __restrict__ s,
    u16* __restrict__ d, long n)
{
  long i = ((long)blockIdx.x*256 + threadIdx.x)*8;
  if (i >= n) return;
  float4 a = *(const float4*)(s+i);
  float4 b = *(const float4*)(s+i+4);
  union { __hip_bfloat162 h[4]; uint4 v; } o;
  o.h[0] = __float22bfloat162_rn(make_float2(a.x,a.y));
  o.h[1] = __float22bfloat162_rn(make_float2(a.z,a.w));
  o.h[2] = __float22bfloat162_rn(make_float2(b.x,b.y));
  o.h[3] = __float22bfloat162_rn(make_float2(b.z,b.w));
  *(uint4*)(d+i) = o.v;
}

// dual fp32->bf16 convert (merges two regions into one dispatch)
__global__ __launch_bounds__(256) void cvt2(
    const float* __restrict__ s1, u16* __restrict__ d1, long n1,
    const float* __restrict__ s2, u16* __restrict__ d2, long n2)
{
  long i = ((long)blockIdx.x*256 + threadIdx.x)*8;
  const float* s; u16* d; long k;
  if (i < n1){ s = s1; d = d1; k = i; }
  else { k = i - n1; if (k >= n2) return; s = s2; d = d2; }
  float4 a = *(const float4*)(s+k);
  float4 b = *(const float4*)(s+k+4);
  union { __hip_bfloat162 h[4]; uint4 v; } o;
  o.h[0] = __float22bfloat162_rn(make_float2(a.x,a.y));
  o.h[1] = __float22bfloat162_rn(make_float2(a.z,a.w));
  o.h[2] = __float22bfloat162_rn(make_float2(b.x,b.y));
  o.h[3] = __float22bfloat162_rn(make_float2(b.z,b.w));
  *(uint4*)(d+k) = o.v;
}

__global__ __launch_bounds__(256) void init_x_kernel(const float* __restrict__ h,
    float* __restrict__ x, int n)
{
  int i = blockIdx.x*256 + threadIdx.x;
  if (i < n) x[i] = h[i];
  else if (i == n) x[i] = 0.f;   // aux slot
}

// plain LN (layer 0's ln1): bf16 out
__global__ __launch_bounds__(256) void ln_kernel(const float* __restrict__ x,
    const float* __restrict__ s, const float* __restrict__ b,
    __hip_bfloat16* __restrict__ ob)
{
  int row = blockIdx.x, tid = threadIdx.x;
  const float* xr = x + (long)row*TC;
  int c = tid*4;
  float4 xv = *(const float4*)(xr + c);
  float sum = xv.x+xv.y+xv.z+xv.w;
  float sq = xv.x*xv.x+xv.y*xv.y+xv.z*xv.z+xv.w*xv.w;
  #pragma unroll
  for (int o=32;o;o>>=1){ sum += __shfl_down(sum,o); sq += __shfl_down(sq,o); }
  __shared__ float ls[8];
  if ((tid&63)==0){ ls[tid>>6] = sum; ls[4+(tid>>6)] = sq; }
  __syncthreads();
  float mean = (ls[0]+ls[1]+ls[2]+ls[3]) * (1.f/TC);
  float ex2  = (ls[4]+ls[5]+ls[6]+ls[7]) * (1.f/TC);
  float rstd = rsqrtf(ex2 - mean*mean + 1e-6f);
  float4 sv = *(const float4*)(s + c);
  float4 bv = *(const float4*)(b + c);
  float o0 = (xv.x-mean)*rstd*sv.x + bv.x;
  float o1 = (xv.y-mean)*rstd*sv.y + bv.y;
  float o2 = (xv.z-mean)*rstd*sv.z + bv.z;
  float o3 = (xv.w-mean)*rstd*sv.w + bv.w;
  __hip_bfloat16* op = ob + (long)row*TC + c;
  *reinterpret_cast<__hip_bfloat162*>(op)   = __float22bfloat162_rn(make_float2(o0,o1));
  *reinterpret_cast<__hip_bfloat162*>(op+2) = __float22bfloat162_rn(make_float2(o2,o3));
}

// LN + gate logits fused (MoE); block 0 zeroes counts/psum for routing.
__global__ __launch_bounds__(256) void ln_gate_kernel(const float* __restrict__ x,
    const float* __restrict__ s, const float* __restrict__ b,
    __hip_bfloat16* __restrict__ ob, const float* __restrict__ gw,
    float* __restrict__ logits, int* __restrict__ counts, float* __restrict__ psum)
{
  int row = blockIdx.x, tid = threadIdx.x;
  if (row == 0 && tid < TE){ counts[tid] = 0; psum[tid] = 0.f; }
  const float* xr = x + (long)row*TC;
  int c = tid*4;
  float4 xv = *(const float4*)(xr + c);
  float sum = xv.x+xv.y+xv.z+xv.w;
  float sq = xv.x*xv.x+xv.y*xv.y+xv.z*xv.z+xv.w*xv.w;
  #pragma unroll
  for (int o=32;o;o>>=1){ sum += __shfl_down(sum,o); sq += __shfl_down(sq,o); }
  __shared__ float ls[8];
  if ((tid&63)==0){ ls[tid>>6] = sum; ls[4+(tid>>6)] = sq; }
  __syncthreads();
  float mean = (ls[0]+ls[1]+ls[2]+ls[3]) * (1.f/TC);
  float ex2  = (ls[4]+ls[5]+ls[6]+ls[7]) * (1.f/TC);
  float rstd = rsqrtf(ex2 - mean*mean + 1e-6f);
  float4 sv = *(const float4*)(s + c);
  float4 bv = *(const float4*)(b + c);
  float o0 = (xv.x-mean)*rstd*sv.x + bv.x;
  float o1 = (xv.y-mean)*rstd*sv.y + bv.y;
  float o2 = (xv.z-mean)*rstd*sv.z + bv.z;
  float o3 = (xv.w-mean)*rstd*sv.w + bv.w;
  __hip_bfloat16* op = ob + (long)row*TC + c;
  *reinterpret_cast<__hip_bfloat162*>(op)   = __float22bfloat162_rn(make_float2(o0,o1));
  *reinterpret_cast<__hip_bfloat162*>(op+2) = __float22bfloat162_rn(make_float2(o2,o3));
  __shared__ float gs[4];
  #pragma unroll
  for (int e=0;e<TE;e++){
    float4 wv = *(const float4*)(gw + (long)e*TC + c);
    float pr = o0*wv.x + o1*wv.y + o2*wv.z + o3*wv.w;
    #pragma unroll
    for (int o=32;o;o>>=1) pr += __shfl_down(pr,o);
    if ((tid&63)==0) gs[tid>>6] = pr;
    __syncthreads();
    if (tid==0) logits[(long)row*TE + e] = gs[0]+gs[1]+gs[2]+gs[3];
    __syncthreads();
  }
}

// 10-block routing (r12-verified): global counts atomics, per-block psum.
__global__ __launch_bounds__(256) void routing_kernel(const float* __restrict__ logits,
    int* __restrict__ counts, int* __restrict__ etok,
    int* __restrict__ tEt, int* __restrict__ tPt, float* __restrict__ tGt,
    float* __restrict__ psum)
{
  __shared__ float ps[TE];
  int tid = threadIdx.x;
  if (tid < TE) ps[tid] = 0.f;
  __syncthreads();
  int t = blockIdx.x*256 + tid;
  if (t < TT){
    float pr[TE]; float mx = -3e38f;
    #pragma unroll
    for (int e=0;e<TE;e++){ pr[e] = logits[(long)t*TE+e]; mx = fmaxf(mx, pr[e]); }
    float sum = 0.f;
    #pragma unroll
    for (int e=0;e<TE;e++){ pr[e] = __expf(pr[e]-mx); sum += pr[e]; }
    float inv = 1.f/sum;
    #pragma unroll
    for (int e=0;e<TE;e++) pr[e] *= inv;
    int i1 = 0;
    #pragma unroll
    for (int e=1;e<TE;e++) if (pr[e] > pr[i1]) i1 = e;
    int i2 = -1;
    #pragma unroll
    for (int e=0;e<TE;e++){ if (e==i1) continue; if (i2<0 || pr[e]>pr[i2]) i2=e; }
    float p1 = pr[i1], p2 = pr[i2];
    float g1 = p1/(p1+p2), g2 = p2/(p1+p2);
    int pos1 = atomicAdd(&counts[i1], 1);
    etok[i1*TT + pos1] = t;
    int pos2 = atomicAdd(&counts[i2], 1);
    etok[i2*TT + pos2] = t;
    tEt[2*t] = i1; tPt[2*t] = pos1; tGt[2*t] = g1;
    tEt[2*t+1] = i2; tPt[2*t+1] = pos2; tGt[2*t+1] = g2;
    #pragma unroll
    for (int e=0;e<TE;e++) atomicAdd(&ps[e], pr[e]);
  }
  __syncthreads();
  if (tid < TE) atomicAdd(&psum[tid], ps[tid]);
}

__global__ void finalize_routing(const int* __restrict__ counts, int* __restrict__ offsets,
    const float* __restrict__ psum, float* __restrict__ aux,
    int* __restrict__ tE1, int* __restrict__ tL1, int* __restrict__ tC1, int* __restrict__ tO1,
    int* __restrict__ tE2, int* __restrict__ tL2, int* __restrict__ tC2, int* __restrict__ tO2)
{
  int off = 0; float a = 0.f; int n1 = 0, n2 = 0;
  for (int e=0;e<TE;e++){
    offsets[e] = off; int c = counts[e];
    for (int j=0;j<c;j+=256){ tE1[n1]=e; tL1[n1]=j; tC1[n1]=c; tO1[n1]=off; n1++; }
    for (int j=0;j<c;j+=128){ tE2[n2]=e; tL2[n2]=j; tC2[n2]=c; tO2[n2]=off; n2++; }
    a += (psum[e]*(1.f/TT)) * ((float)c*(1.f/TT));
    off += c;
  }
  for (;n1<NT1;n1++) tE1[n1] = -1;
  for (;n2<NT2;n2++) tE2[n2] = -1;
  aux[0] += (float)TE * a;
}

__global__ void build_qkv_bias(const float* __restrict__ qb, const float* __restrict__ vb,
    float* __restrict__ out)
{
  int i = blockIdx.x*256 + threadIdx.x;
  if (i >= 3*TC) return;
  float v = 0.f;
  if (i < TC) v = qb[i];
  else if (i >= 2*TC) v = vb[i-2*TC];
  out[i] = v;
}

// x[t] += (g1*sum_k y[k][s1] + g2*sum_k y[k][s2]) * gamma2 (4 split-K chunks);
// optional fused next-ln1.
__global__ __launch_bounds__(256) void combine_ln(
    const u16* __restrict__ y, long yck, const int* __restrict__ tEt,
    const int* __restrict__ tPt, const float* __restrict__ tGt,
    const int* __restrict__ offsets, const float* __restrict__ gamma2,
    float* __restrict__ x,
    const float* __restrict__ ln_s, const float* __restrict__ ln_b,
    __hip_bfloat16* __restrict__ ln_out)
{
  int t = blockIdx.x, tid = threadIdx.x, c = tid*4;
  int e1 = tEt[2*t], e2 = tEt[2*t+1];
  long s1 = (long)(offsets[e1]+tPt[2*t])*TC + c;
  long s2 = (long)(offsets[e2]+tPt[2*t+1])*TC + c;
  float g1 = tGt[2*t], g2 = tGt[2*t+1];
  float ax=0.f, ay=0.f, az=0.f, aw=0.f;
  float bx=0.f, by=0.f, bz=0.f, bw=0.f;
  #pragma unroll
  for (int k=0;k<4;k++){
    ushort4 a = *(const ushort4*)(y + (long)k*yck + s1);
    ushort4 b = *(const ushort4*)(y + (long)k*yck + s2);
    ax += b2f_(a.x); ay += b2f_(a.y); az += b2f_(a.z); aw += b2f_(a.w);
    bx += b2f_(b.x); by += b2f_(b.y); bz += b2f_(b.z); bw += b2f_(b.w);
  }
  float4 gv = *(const float4*)(gamma2 + c);
  float* xp = x + (long)t*TC + c;
  float4 xv = *(const float4*)xp;
  xv.x += (g1*ax + g2*bx)*gv.x;
  xv.y += (g1*ay + g2*by)*gv.y;
  xv.z += (g1*az + g2*bz)*gv.z;
  xv.w += (g1*aw + g2*bw)*gv.w;
  *(float4*)xp = xv;
  if (!ln_out) return;
  float sum = xv.x+xv.y+xv.z+xv.w;
  float sq = xv.x*xv.x+xv.y*xv.y+xv.z*xv.z+xv.w*xv.w;
  #pragma unroll
  for (int o=32;o;o>>=1){ sum += __shfl_down(sum,o); sq += __shfl_down(sq,o); }
  __shared__ float ls[8];
  if ((tid&63)==0){ ls[tid>>6] = sum; ls[4+(tid>>6)] = sq; }
  __syncthreads();
  float mean = (ls[0]+ls[1]+ls[2]+ls[3]) * (1.f/TC);
  float ex2  = (ls[4]+ls[5]+ls[6]+ls[7]) * (1.f/TC);
  float rstd = rsqrtf(ex2 - mean*mean + 1e-6f);
  float4 sv = *(const float4*)(ln_s + c);
  float4 bv = *(const float4*)(ln_b + c);
  float o0 = (xv.x-mean)*rstd*sv.x + bv.x;
  float o1 = (xv.y-mean)*rstd*sv.y + bv.y;
  float o2 = (xv.z-mean)*rstd*sv.z + bv.z;
  float o3 = (xv.w-mean)*rstd*sv.w + bv.w;
  __hip_bfloat16* op = ln_out + (long)t*TC + c;
  *reinterpret_cast<__hip_bfloat162*>(op)   = __float22bfloat162_rn(make_float2(o0,o1));
  *reinterpret_cast<__hip_bfloat162*>(op+2) = __float22bfloat162_rn(make_float2(o2,o3));
}

// ---------------------------------------------------------------------------
extern "C" void kernel_launch(void* const* d_in, const int* in_sizes, int n_in,
                              void* d_out, int out_size, void* d_ws, size_t ws_size,
                              hipStream_t stream) {
  (void)in_sizes; (void)n_in; (void)out_size; (void)ws_size;
  const float* hidden = (const float*)d_in[0];
  const int*   amask  = (const int*)d_in[1];
  const float* rpb    = (const float*)d_in[2];
  const float* qkv_w  = (const float*)d_in[3];
  const float* q_bias = (const float*)d_in[4];
  const float* v_bias = (const float*)d_in[5];
  const float* proj_w = (const float*)d_in[6];
  const float* proj_b = (const float*)d_in[7];
  const float* ln1_s  = (const float*)d_in[8];
  const float* ln1_b  = (const float*)d_in[9];
  const float* ln2_s  = (const float*)d_in[10];
  const float* ln2_b  = (const float*)d_in[11];
  const float* gamma1 = (const float*)d_in[12];
  const float* gamma2 = (const float*)d_in[13];
  const float* gate_w = (const float*)d_in[14];
  const float* fc1_w  = (const float*)d_in[15];
  const float* fc1_b  = (const float*)d_in[16];
  const float* fc2_w  = (const float*)d_in[17];
  const float* fc2_b  = (const float*)d_in[18];

  float* x = (float*)d_out;
  const int NXC = TT*TC;

  char* p = (char*)d_ws;
  auto alloc = [&](size_t bytes)->void* {
    void* r = (void*)p; p += (bytes + 255) & ~(size_t)255; return r;
  };
  float* qkvbias = (float*)alloc(3*TC*4);
  u16*   ln_bf   = (u16*)alloc((size_t)TT*TC*2);
  float* logits  = (float*)alloc((size_t)TT*TE*4);
  int*   counts  = (int*)alloc(TE*4);
  int*   offsets = (int*)alloc(TE*4);
  float* psum    = (float*)alloc(TE*4);
  int*   etok    = (int*)alloc((size_t)TE*TT*4);
  int*   tEt     = (int*)alloc((size_t)2*TT*4);
  int*   tPt     = (int*)alloc((size_t)2*TT*4);
  float* tGt     = (float*)alloc((size_t)2*TT*4);
  int*   tE1 = (int*)alloc(NT1*4); int* tL1 = (int*)alloc(NT1*4);
  int*   tC1 = (int*)alloc(NT1*4); int* tO1 = (int*)alloc(NT1*4);
  int*   tE2 = (int*)alloc(NT2*4); int* tL2 = (int*)alloc(NT2*4);
  int*   tC2 = (int*)alloc(NT2*4); int* tO2 = (int*)alloc(NT2*4);
  u16*   rpb16   = (u16*)alloc((size_t)TH*TN*TN*2);          // 13.1 MB
  char* arena = (char*)alloc(220200960);
  // attention phase (high region)
  u16*   qkv_bf  = (u16*)(arena + 157286400);               //  15,728,640
  u16*   vT      = (u16*)(arena + 183500800);               //   5,242,880
  u16*   attn_o  = (u16*)(arena + 188743680);               //   5,242,880
  u16*   wqkv    = (u16*)(arena + 193986560);               //   6,291,456
  u16*   wproj   = (u16*)(arena + 200278016);               //   2,097,152
  // MoE phase (overlays attention-phase low region — dead by then)
  u16*   fc1b    = (u16*)(arena);                           //  67,108,864
  u16*   fc2b    = (u16*)(arena + 67108864);                //  67,108,864
  u16*   h1      = (u16*)(arena + 134217728);               //  41,943,040 (5120 x TI bf16)
  u16*   yslot   = (u16*)(arena + 176160768);               //  41,943,040 (4 x 5120 x TC bf16)
  const long YCK = (long)5120*TC;

  init_x_kernel<<<(NXC+1+255)/256, 256, 0, stream>>>(hidden, x, NXC);
  cvt_kernel<<<(TH*TN*TN)/2048, 256, 0, stream>>>(rpb, rpb16, (long)TH*TN*TN);

  for (int l=0;l<2;l++){
    // --- attention ---
    if (l == 0)
      ln_kernel<<<TT, 256, 0, stream>>>(x, ln1_s, ln1_b, (__hip_bfloat16*)ln_bf);
    build_qkv_bias<<<(3*TC+255)/256, 256, 0, stream>>>(q_bias + l*TC, v_bias + l*TC, qkvbias);
    cvt2<<<(4*TC*TC)/2048, 256, 0, stream>>>(
        qkv_w + (size_t)l*3*TC*TC, wqkv, (long)3*TC*TC,
        proj_w + (size_t)l*TC*TC, wproj, (long)TC*TC);
    // qkv: 128x128 tiles, 480 blocks, 64KB LDS -> 2 blocks/CU
    gemm8<128,128,0,1><<<dim3(20*24,1,1), 512, 0, stream>>>(
        ln_bf, wqkv, qkv_bf, qkvbias, 0,
        nullptr, nullptr, nullptr, nullptr, nullptr,
        TT, TC, TC, 20, 3*TC, 0, 0);
    v_transpose<<<dim3(TN/128, TBH), 256, 0, stream>>>(qkv_bf, vT);
    // fattn: 64-row q-tiles, 640 blocks, ~49KB LDS
    fattn<<<dim3(TBH*10,1,1), 256, 0, stream>>>(qkv_bf, vT, rpb16, amask, attn_o);
    cvt2<<<(2*TE*TI*TC)/2048, 256, 0, stream>>>(
        fc1_w + (size_t)l*TE*TI*TC, fc1b, (long)TE*TI*TC,
        fc2_w + (size_t)l*TE*TC*TI, fc2b, (long)TE*TC*TI);
    gemm_bt<64,128,2><<<dim3(8*40,1,1), 256, 0, stream>>>(
        attn_o, wproj, x, proj_b + l*TC, gamma1 + l*TC,
        TT, TC, 40, TC);

    // --- MoE ---
    ln_gate_kernel<<<TT, 256, 0, stream>>>(x, ln2_s + l*TC, ln2_b + l*TC,
        (__hip_bfloat16*)ln_bf, gate_w + (size_t)l*TE*TC, logits, counts, psum);
    routing_kernel<<<(TT+255)/256, 256, 0, stream>>>(logits, counts, etok, tEt, tPt, tGt, psum);
    finalize_routing<<<1, 1, 0, stream>>>(counts, offsets, psum, x + NXC,
        tE1, tL1, tC1, tO1, tE2, tL2, tC2, tO2);
    // fc1: 128x128 tiles (64KB LDS -> 2 blocks/CU), gather, gelu
    gemm8<128,128,1,3><<<dim3(32*NT2,1,1), 512, 0, stream>>>(
        ln_bf, fc1b, h1, fc1_b + (size_t)l*TE*TI, TI,
        tE2, tL2, tC2, tO2, etok,
        0, TC, TC, 32, TI, (long)TI*TC, 0);
    // fc2: 128x128 tiles, compact rows, split-K=4 -> 1536 blocks (3 clean
    // rounds at 2 blocks/CU; removes the 1.5-round tail of split-K=2)
    gemm8<128,128,2,1><<<dim3(8*NT2,1,4), 512, 0, stream>>>(
        h1, fc2b, yslot, fc2_b + (size_t)l*TE*TC, TC,
        tE2, tL2, tC2, tO2, nullptr,
        0, TI, TI/4, 8, TC, (long)TC*TI, YCK);
    // combine (sums 4 split-K chunks) + (for l=0) fused ln1 of next layer
    combine_ln<<<TT, 256, 0, stream>>>(yslot, YCK, tEt, tPt, tGt, offsets,
        gamma2 + l*TC, x,
        ln1_s + (l+1)*TC, ln1_b + (l+1)*TC,
        (l == 0) ? (__hip_bfloat16*)ln_bf : nullptr);
  }
}

// Round 19
// 784.969 us; speedup vs baseline: 1.0146x; 1.0146x over previous
//
#include <hip/hip_runtime.h>
#include <hip/hip_bf16.h>

#define TB 4
#define TN 640
#define TC 1024
#define TH 16
#define THD 64
#define TI 4096
#define TE 8
#define TT (TB*TN)     /* 2560 tokens */
#define TBH (TB*TH)    /* 64 */
#define SCALE_ 0.125f
#define NT1 32
#define NT2 48         /* cap: 128-row tiles across experts */

typedef unsigned short u16;
typedef __bf16 bf16x8 __attribute__((ext_vector_type(8)));
typedef float f32x4 __attribute__((ext_vector_type(4)));

__device__ __forceinline__ float gelu_tanh(float v){
  float t = 0.7978845608f*(v + 0.044715f*v*v*v);
  float e = __expf(2.f*t);
  return 0.5f*v*(1.f + (1.f - 2.f/(e + 1.f)));
}
__device__ __forceinline__ float b2f_(u16 u){
  union{float f;unsigned i;} v; v.i = (unsigned)u<<16; return v.f;
}

// ---------------------------------------------------------------------------
// 8-wave bf16 GEMM (r8/r12/r16-verified): static double buffers + one
// __syncthreads per K-step, STAGE-first. XOR-8 source+read swizzle.
// MODE 0: plain rows. MODE 1: tile-mapped gather (fc1). MODE 2: tile-mapped
// compact rows (fc2). EPI 1: bf16 (+bias if kc==0); EPI 3: gelu->bf16.
// ---------------------------------------------------------------------------
template<int BM,int BN,int MODE,int EPI>
__global__ __launch_bounds__(512) void gemm8(
    const u16* __restrict__ A, const u16* __restrict__ Wb, void* __restrict__ Cout,
    const float* __restrict__ bias, long biasStride,
    const int* __restrict__ tE, const int* __restrict__ tL,
    const int* __restrict__ tC, const int* __restrict__ tO,
    const int* __restrict__ etok,
    int M, int Kfull, int Kchunk, int n0, int ldc, long sW, long sCk)
{
  constexpr int FM = BM/32, FN = BN/64;
  constexpr int AI = BM/64, BI = BN/64;

  const int nwg = gridDim.x;
  int lin = blockIdx.x;
  int q = nwg >> 3, r = nwg & 7;
  int xcd = lin & 7, pos = lin >> 3;
  int swz = (xcd < r ? xcd*(q+1) : r*(q+1) + (xcd-r)*q) + pos;
  const int id0 = swz % n0, id1 = swz / n0;

  int e, loc0, cnt, off0, bx;
  if constexpr (MODE == 0){
    e = 0; loc0 = id0*BM; cnt = M; off0 = 0; bx = id1;
  } else {
    bx = id0;
    e = tE[id1]; if (e < 0) return;
    loc0 = tL[id1]; cnt = tC[id1]; off0 = tO[id1];
  }
  const int kc = blockIdx.z;
  const long kbase = (long)kc * Kchunk;

  const int tid = threadIdx.x, w = tid>>6, lane = tid&63;
  const int wm = w>>2, wn = w&3;

  __shared__ __align__(16) u16 As0[BM*64], As1[BM*64];
  __shared__ __align__(16) u16 Bs0[BN*64], Bs1[BN*64];

  const u16* Wz = Wb + (long)e*sW;

  const int c16 = (lane&7) ^ ((lane>>3)&7);
  long a_src[AI];
  #pragma unroll
  for (int j=0;j<AI;j++){
    int li = (w*AI+j)*8 + (lane>>3);
    int row;
    if constexpr (MODE == 0){
      row = loc0 + li;
    } else {
      int ll = loc0 + li; if (ll > cnt-1) ll = cnt-1;
      if constexpr (MODE == 1) row = etok[e*TT + ll];
      else                     row = off0 + ll;
    }
    a_src[j] = (long)row*Kfull + kbase + c16*8;
  }
  long b_src[BI];
  #pragma unroll
  for (int j=0;j<BI;j++){
    int rr = bx*BN + (w*BI+j)*8 + (lane>>3);
    b_src[j] = (long)rr*Kfull + kbase + c16*8;
  }

  auto STAGE = [&](u16 (&Ad)[BM*64], u16 (&Bd)[BN*64], int t){
    #pragma unroll
    for (int j=0;j<AI;j++)
      __builtin_amdgcn_global_load_lds(
        (const __attribute__((address_space(1))) void*)(A + a_src[j] + t*64),
        (__attribute__((address_space(3))) void*)(&Ad[(w*AI+j)*512]), 16, 0, 0);
    #pragma unroll
    for (int j=0;j<BI;j++)
      __builtin_amdgcn_global_load_lds(
        (const __attribute__((address_space(1))) void*)(Wz + b_src[j] + t*64),
        (__attribute__((address_space(3))) void*)(&Bd[(w*BI+j)*512]), 16, 0, 0);
  };

  f32x4 acc[FM][FN];
  #pragma unroll
  for (int m=0;m<FM;m++)
    #pragma unroll
    for (int n=0;n<FN;n++) acc[m][n] = (f32x4){0.f,0.f,0.f,0.f};

  const int lr = lane & 15;
  const int s0 = (lane>>4) ^ (lane&7);
  const int abase = lr*128 + s0*16;

  auto COMP = [&](const u16 (&As)[BM*64], const u16 (&Bs)[BN*64]){
    const char* Ab = (const char*)&As[0];
    const char* Bb = (const char*)&Bs[0];
    bf16x8 af[FM][2], bfr[FN][2];
    #pragma unroll
    for (int m=0;m<FM;m++){
      af[m][0] = *reinterpret_cast<const bf16x8*>(Ab + wm*(BM/2)*128 + m*2048 + abase);
      af[m][1] = *reinterpret_cast<const bf16x8*>(Ab + wm*(BM/2)*128 + m*2048 + (abase^64));
    }
    #pragma unroll
    for (int n=0;n<FN;n++){
      bfr[n][0] = *reinterpret_cast<const bf16x8*>(Bb + wn*(BN/4)*128 + n*2048 + abase);
      bfr[n][1] = *reinterpret_cast<const bf16x8*>(Bb + wn*(BN/4)*128 + n*2048 + (abase^64));
    }
    #pragma unroll
    for (int m=0;m<FM;m++)
      #pragma unroll
      for (int n=0;n<FN;n++){
        acc[m][n] = __builtin_amdgcn_mfma_f32_16x16x32_bf16(af[m][0], bfr[n][0], acc[m][n], 0,0,0);
        acc[m][n] = __builtin_amdgcn_mfma_f32_16x16x32_bf16(af[m][1], bfr[n][1], acc[m][n], 0,0,0);
      }
  };

  const int nt = Kchunk >> 6;
  STAGE(As0, Bs0, 0);
  __syncthreads();
  for (int t=0; t<nt; t+=2){
    if (t+1 < nt) STAGE(As1, Bs1, t+1);
    COMP(As0, Bs0);
    __syncthreads();
    if (t+1 < nt){
      if (t+2 < nt) STAGE(As0, Bs0, t+2);
      COMP(As1, Bs1);
      __syncthreads();
    }
  }

  const float* bz = (bias && kc==0) ? (bias + (long)e*biasStride) : nullptr;
  #pragma unroll
  for (int m=0;m<FM;m++){
    #pragma unroll
    for (int n=0;n<FN;n++){
      int gcol = bx*BN + wn*(BN/4) + n*16 + (lane&15);
      float bv = bz ? bz[gcol] : 0.f;
      #pragma unroll
      for (int jj=0;jj<4;jj++){
        int li = wm*(BM/2) + m*16 + (lane>>4)*4 + jj;
        int ll = loc0 + li;
        if (MODE != 0 && ll >= cnt) continue;
        float v = acc[m][n][jj] + bv;
        if constexpr (EPI == 3) v = gelu_tanh(v);
        long orow = (MODE == 0) ? (long)ll : (long)(off0 + ll);
        ((__hip_bfloat16*)Cout)[kc*sCk + orow*ldc + gcol] = __float2bfloat16(v);
      }
    }
  }
}

// ---------------------------------------------------------------------------
// 4-wave GEMM (proj), r8 structure.  EPI 2: resadd x += v*scalevec (RMW)
// ---------------------------------------------------------------------------
template<int BM,int BN,int EPI>
__global__ __launch_bounds__(256) void gemm_bt(
    const u16* __restrict__ A, const u16* __restrict__ Wb, void* __restrict__ Cout,
    const float* __restrict__ bias, const float* __restrict__ scalevec,
    int M, int Kfull, int nby, int ldc)
{
  constexpr int FM = BM/32, FN = BN/32;
  constexpr int AI = BM/32, BI = BN/32;

  const int nwg = gridDim.x;
  int lin = blockIdx.x;
  int q = nwg >> 3, r = nwg & 7;
  int xcd = lin & 7, pos = lin >> 3;
  int swz = (xcd < r ? xcd*(q+1) : r*(q+1) + (xcd-r)*q) + pos;
  const int bx = swz / nby;
  const int by = swz - bx*nby;
  if (by*BM >= M) return;

  const int tid = threadIdx.x, w = tid>>6, lane = tid&63;
  const int wm = w>>1, wn = w&1;

  __shared__ __align__(16) u16 As0[BM*64], As1[BM*64];
  __shared__ __align__(16) u16 Bs0[BN*64], Bs1[BN*64];

  const int c16 = (lane&7) ^ ((lane>>3)&7);
  long a_src[AI];
  #pragma unroll
  for (int j=0;j<AI;j++){
    int i = by*BM + (w*AI+j)*8 + (lane>>3);
    a_src[j] = (long)i*Kfull + c16*8;
  }
  long b_src[BI];
  #pragma unroll
  for (int j=0;j<BI;j++){
    int rr = bx*BN + (w*BI+j)*8 + (lane>>3);
    b_src[j] = (long)rr*Kfull + c16*8;
  }

  auto STAGE = [&](u16 (&Ad)[BM*64], u16 (&Bd)[BN*64], int t){
    #pragma unroll
    for (int j=0;j<AI;j++)
      __builtin_amdgcn_global_load_lds(
        (const __attribute__((address_space(1))) void*)(A + a_src[j] + t*64),
        (__attribute__((address_space(3))) void*)(&Ad[(w*AI+j)*512]), 16, 0, 0);
    #pragma unroll
    for (int j=0;j<BI;j++)
      __builtin_amdgcn_global_load_lds(
        (const __attribute__((address_space(1))) void*)(Wb + b_src[j] + t*64),
        (__attribute__((address_space(3))) void*)(&Bd[(w*BI+j)*512]), 16, 0, 0);
  };

  f32x4 acc[FM][FN];
  #pragma unroll
  for (int m=0;m<FM;m++)
    #pragma unroll
    for (int n=0;n<FN;n++) acc[m][n] = (f32x4){0.f,0.f,0.f,0.f};

  const int lr = lane & 15;
  const int s0 = (lane>>4) ^ (lane&7);
  const int abase = lr*128 + s0*16;

  auto COMP = [&](const u16 (&As)[BM*64], const u16 (&Bs)[BN*64]){
    const char* Ab = (const char*)&As[0];
    const char* Bb = (const char*)&Bs[0];
    bf16x8 af[FM][2], bfr[FN][2];
    #pragma unroll
    for (int m=0;m<FM;m++){
      af[m][0] = *reinterpret_cast<const bf16x8*>(Ab + wm*(BM/2)*128 + m*2048 + abase);
      af[m][1] = *reinterpret_cast<const bf16x8*>(Ab + wm*(BM/2)*128 + m*2048 + (abase^64));
    }
    #pragma unroll
    for (int n=0;n<FN;n++){
      bfr[n][0] = *reinterpret_cast<const bf16x8*>(Bb + wn*(BN/2)*128 + n*2048 + abase);
      bfr[n][1] = *reinterpret_cast<const bf16x8*>(Bb + wn*(BN/2)*128 + n*2048 + (abase^64));
    }
    #pragma unroll
    for (int m=0;m<FM;m++)
      #pragma unroll
      for (int n=0;n<FN;n++){
        acc[m][n] = __builtin_amdgcn_mfma_f32_16x16x32_bf16(af[m][0], bfr[n][0], acc[m][n], 0,0,0);
        acc[m][n] = __builtin_amdgcn_mfma_f32_16x16x32_bf16(af[m][1], bfr[n][1], acc[m][n], 0,0,0);
      }
  };

  const int nt = Kfull >> 6;
  STAGE(As0, Bs0, 0);
  __syncthreads();
  for (int t=0; t<nt; t+=2){
    if (t+1 < nt) STAGE(As1, Bs1, t+1);
    COMP(As0, Bs0);
    __syncthreads();
    if (t+1 < nt){
      if (t+2 < nt) STAGE(As0, Bs0, t+2);
      COMP(As1, Bs1);
      __syncthreads();
    }
  }

  #pragma unroll
  for (int m=0;m<FM;m++){
    #pragma unroll
    for (int n=0;n<FN;n++){
      int gcol = bx*BN + wn*(BN/2) + n*16 + (lane&15);
      float bv = bias ? bias[gcol] : 0.f;
      #pragma unroll
      for (int jj=0;jj<4;jj++){
        int i = by*BM + wm*(BM/2) + m*16 + (lane>>4)*4 + jj;
        float v = acc[m][n][jj] + bv;
        float* p = (float*)Cout + (long)i*ldc + gcol;
        *p += v * scalevec[gcol];
      }
    }
  }
}

// ---------------------------------------------------------------------------
// Fused flash attention, 64-row Q-tiles (r17-verified): per block (bh, qt),
// 4 waves x 16 q-rows. Q/K direct from qkv_bf; V^T from vT; rpb bf16.
// ---------------------------------------------------------------------------
__global__ __launch_bounds__(256) void fattn(
    const u16* __restrict__ qkv, const u16* __restrict__ vT,
    const u16* __restrict__ rpb16, const int* __restrict__ mask, u16* __restrict__ attn_o)
{
  const int blk = blockIdx.x;
  const int bh = blk / 10, qt = blk - bh*10;
  const int b = bh >> 4, h = bh & 15;
  const int q0 = qt * 64;
  const int tid = threadIdx.x, w = tid >> 6, lane = tid & 63;

  __shared__ __align__(16) u16 Qs[64*64];
  __shared__ __align__(16) u16 Ks0[64*64], Ks1[64*64];
  __shared__ __align__(16) u16 Vs0[64*64], Vs1[64*64];
  __shared__ __align__(16) u16 Ps[4][16*72];

  const int c16 = (lane&7) ^ ((lane>>3)&7);
  const long qkbase = (long)h*THD;
  #pragma unroll
  for (int j=0;j<2;j++){
    int row = (w*2+j)*8 + (lane>>3);
    __builtin_amdgcn_global_load_lds(
      (const __attribute__((address_space(1))) void*)(qkv + (long)(b*TN + q0 + row)*(3*TC) + qkbase + c16*8),
      (__attribute__((address_space(3))) void*)(&Qs[(w*2+j)*512]), 16, 0, 0);
  }

  auto STAGE = [&](u16 (&Kd)[64*64], u16 (&Vd)[64*64], int k0){
    #pragma unroll
    for (int j=0;j<2;j++){
      int row = (w*2+j)*8 + (lane>>3);
      __builtin_amdgcn_global_load_lds(
        (const __attribute__((address_space(1))) void*)(qkv + (long)(b*TN + k0 + row)*(3*TC) + TC + qkbase + c16*8),
        (__attribute__((address_space(3))) void*)(&Kd[(w*2+j)*512]), 16, 0, 0);
      __builtin_amdgcn_global_load_lds(
        (const __attribute__((address_space(1))) void*)(vT + ((long)bh*THD + row)*TN + k0 + c16*8),
        (__attribute__((address_space(3))) void*)(&Vd[(w*2+j)*512]), 16, 0, 0);
    }
  };

  const int s0 = (lane>>4) ^ (lane&7);
  const int lr = lane & 15;

  f32x4 acc_o[4];
  #pragma unroll
  for (int nd=0;nd<4;nd++) acc_o[nd] = (f32x4){0.f,0.f,0.f,0.f};
  float m_r[4], l_r[4];
  #pragma unroll
  for (int jj=0;jj<4;jj++){ m_r[jj] = -3e38f; l_r[jj] = 0.f; }

  auto TILE = [&](const u16 (&Ks)[64*64], const u16 (&Vs)[64*64], int k0){
    const char* Qb = (const char*)&Qs[0];
    const char* Kb = (const char*)&Ks[0];
    const char* Vb = (const char*)&Vs[0];
    bf16x8 qa[2], kf[4][2];
    {
      int row = w*16 + lr;
      qa[0] = *reinterpret_cast<const bf16x8*>(Qb + row*128 + s0*16);
      qa[1] = *reinterpret_cast<const bf16x8*>(Qb + row*128 + (s0*16^64));
    }
    #pragma unroll
    for (int nk=0;nk<4;nk++){
      int row = nk*16 + lr;
      kf[nk][0] = *reinterpret_cast<const bf16x8*>(Kb + row*128 + s0*16);
      kf[nk][1] = *reinterpret_cast<const bf16x8*>(Kb + row*128 + (s0*16^64));
    }
    f32x4 acc_s[4];
    #pragma unroll
    for (int nk=0;nk<4;nk++){
      acc_s[nk] = (f32x4){0.f,0.f,0.f,0.f};
      acc_s[nk] = __builtin_amdgcn_mfma_f32_16x16x32_bf16(qa[0], kf[nk][0], acc_s[nk], 0,0,0);
      acc_s[nk] = __builtin_amdgcn_mfma_f32_16x16x32_bf16(qa[1], kf[nk][1], acc_s[nk], 0,0,0);
    }
    float sc[4];
    #pragma unroll
    for (int jj=0;jj<4;jj++){
      int qrow = q0 + w*16 + (lane>>4)*4 + jj;
      float s[4];
      #pragma unroll
      for (int nk=0;nk<4;nk++){
        int kg = k0 + nk*16 + lr;
        float t = acc_s[nk][jj]*SCALE_ + b2f_(rpb16[((long)h*TN + qrow)*TN + kg]);
        if (mask[b*TN + kg] == 0) t = -1e30f;
        s[nk] = t;
      }
      float mx = fmaxf(fmaxf(s[0],s[1]), fmaxf(s[2],s[3]));
      #pragma unroll
      for (int o=1;o<16;o<<=1) mx = fmaxf(mx, __shfl_xor(mx, o));
      float mnew = fmaxf(m_r[jj], mx);
      float scale = __expf(m_r[jj] - mnew);
      float rs = 0.f;
      #pragma unroll
      for (int nk=0;nk<4;nk++){ s[nk] = __expf(s[nk] - mnew); rs += s[nk]; }
      #pragma unroll
      for (int o=1;o<16;o<<=1) rs += __shfl_xor(rs, o);
      l_r[jj] = l_r[jj]*scale + rs;
      m_r[jj] = mnew;
      sc[jj] = scale;
      int qloc = (lane>>4)*4 + jj;
      #pragma unroll
      for (int nk=0;nk<4;nk++)
        Ps[w][qloc*72 + nk*16 + lr] = (u16)__bfloat16_as_ushort(__float2bfloat16(s[nk]));
    }
    f32x4 sv = (f32x4){sc[0], sc[1], sc[2], sc[3]};
    #pragma unroll
    for (int nd=0;nd<4;nd++) acc_o[nd] *= sv;

    const char* Pw = (const char*)&Ps[w][0];
    bf16x8 pa[2], vb[4][2];
    {
      int qloc = lr;
      pa[0] = *reinterpret_cast<const bf16x8*>(Pw + qloc*144 + (lane>>4)*16);
      pa[1] = *reinterpret_cast<const bf16x8*>(Pw + qloc*144 + (lane>>4)*16 + 64);
    }
    #pragma unroll
    for (int nd=0;nd<4;nd++){
      int row = nd*16 + lr;
      vb[nd][0] = *reinterpret_cast<const bf16x8*>(Vb + row*128 + s0*16);
      vb[nd][1] = *reinterpret_cast<const bf16x8*>(Vb + row*128 + (s0*16^64));
    }
    #pragma unroll
    for (int nd=0;nd<4;nd++){
      acc_o[nd] = __builtin_amdgcn_mfma_f32_16x16x32_bf16(pa[0], vb[nd][0], acc_o[nd], 0,0,0);
      acc_o[nd] = __builtin_amdgcn_mfma_f32_16x16x32_bf16(pa[1], vb[nd][1], acc_o[nd], 0,0,0);
    }
  };

  STAGE(Ks0, Vs0, 0);
  __syncthreads();
  for (int t=0; t<10; t+=2){
    if (t+1 < 10) STAGE(Ks1, Vs1, (t+1)*64);
    TILE(Ks0, Vs0, t*64);
    __syncthreads();
    if (t+1 < 10){
      if (t+2 < 10) STAGE(Ks0, Vs0, (t+2)*64);
      TILE(Ks1, Vs1, (t+1)*64);
      __syncthreads();
    }
  }

  {
    float linv[4];
    #pragma unroll
    for (int jj=0;jj<4;jj++) linv[jj] = 1.f / l_r[jj];
    #pragma unroll
    for (int nd=0;nd<4;nd++){
      #pragma unroll
      for (int jj=0;jj<4;jj++){
        int qg = q0 + w*16 + (lane>>4)*4 + jj;
        int dg = h*THD + nd*16 + lr;
        attn_o[(long)(b*TN + qg)*TC + dg] =
          (u16)__bfloat16_as_ushort(__float2bfloat16(acc_o[nd][jj]*linv[jj]));
      }
    }
  }
}

// grid (5, TBH): LDS-transpose v section of qkv_bf into vT[bh][d][n]
__global__ __launch_bounds__(256) void v_transpose(const u16* __restrict__ qkv,
    u16* __restrict__ vT)
{
  const int bh = blockIdx.y, b = bh>>4, h = bh&15;
  const int n0 = blockIdx.x*128;
  const int tid = threadIdx.x;
  __shared__ u16 vt[128][72];
  #pragma unroll
  for (int j=0;j<4;j++){
    int f = j*2048 + tid*8;
    int r = f>>6, d = f&63;
    *(uint4*)(&vt[r][d]) = *(const uint4*)(qkv + (long)(b*TN + n0 + r)*(3*TC) + 2*TC + h*THD + d);
  }
  __syncthreads();
  #pragma unroll
  for (int j=0;j<4;j++){
    int f = j*2048 + tid*8;
    int dr = f>>7, nc = f&127;
    union { uint4 v; u16 u[8]; } o;
    #pragma unroll
    for (int e=0;e<8;e++) o.u[e] = vt[nc+e][dr];
    *(uint4*)(vT + ((long)bh*THD + dr)*TN + n0 + nc) = o.v;
  }
}

// ---------------------------------------------------------------------------
__global__ __launch_bounds__(256) void cvt_kernel(const float* __restrict__ s,
    u16* __restrict__ d, long n)
{
  long i = ((long)blockIdx.x*256 + threadIdx.x)*8;
  if (i >= n) return;
  float4 a = *(const float4*)(s+i);
  float4 b = *(const float4*)(s+i+4);
  union { __hip_bfloat162 h[4]; uint4 v; } o;
  o.h[0] = __float22bfloat162_rn(make_float2(a.x,a.y));
  o.h[1] = __float22bfloat162_rn(make_float2(a.z,a.w));
  o.h[2] = __float22bfloat162_rn(make_float2(b.x,b.y));
  o.h[3] = __float22bfloat162_rn(make_float2(b.z,b.w));
  *(uint4*)(d+i) = o.v;
}

// dual fp32->bf16 convert (merges two regions into one dispatch)
__global__ __launch_bounds__(256) void cvt2(
    const float* __restrict__ s1, u16* __restrict__ d1, long n1,
    const float* __restrict__ s2, u16* __restrict__ d2, long n2)
{
  long i = ((long)blockIdx.x*256 + threadIdx.x)*8;
  const float* s; u16* d; long k;
  if (i < n1){ s = s1; d = d1; k = i; }
  else { k = i - n1; if (k >= n2) return; s = s2; d = d2; }
  float4 a = *(const float4*)(s+k);
  float4 b = *(const float4*)(s+k+4);
  union { __hip_bfloat162 h[4]; uint4 v; } o;
  o.h[0] = __float22bfloat162_rn(make_float2(a.x,a.y));
  o.h[1] = __float22bfloat162_rn(make_float2(a.z,a.w));
  o.h[2] = __float22bfloat162_rn(make_float2(b.x,b.y));
  o.h[3] = __float22bfloat162_rn(make_float2(b.z,b.w));
  *(uint4*)(d+k) = o.v;
}

__global__ __launch_bounds__(256) void init_x_kernel(const float* __restrict__ h,
    float* __restrict__ x, int n)
{
  int i = blockIdx.x*256 + threadIdx.x;
  if (i < n) x[i] = h[i];
  else if (i == n) x[i] = 0.f;   // aux slot
}

// plain LN (layer 0's ln1): bf16 out
__global__ __launch_bounds__(256) void ln_kernel(const float* __restrict__ x,
    const float* __restrict__ s, const float* __restrict__ b,
    __hip_bfloat16* __restrict__ ob)
{
  int row = blockIdx.x, tid = threadIdx.x;
  const float* xr = x + (long)row*TC;
  int c = tid*4;
  float4 xv = *(const float4*)(xr + c);
  float sum = xv.x+xv.y+xv.z+xv.w;
  float sq = xv.x*xv.x+xv.y*xv.y+xv.z*xv.z+xv.w*xv.w;
  #pragma unroll
  for (int o=32;o;o>>=1){ sum += __shfl_down(sum,o); sq += __shfl_down(sq,o); }
  __shared__ float ls[8];
  if ((tid&63)==0){ ls[tid>>6] = sum; ls[4+(tid>>6)] = sq; }
  __syncthreads();
  float mean = (ls[0]+ls[1]+ls[2]+ls[3]) * (1.f/TC);
  float ex2  = (ls[4]+ls[5]+ls[6]+ls[7]) * (1.f/TC);
  float rstd = rsqrtf(ex2 - mean*mean + 1e-6f);
  float4 sv = *(const float4*)(s + c);
  float4 bv = *(const float4*)(b + c);
  float o0 = (xv.x-mean)*rstd*sv.x + bv.x;
  float o1 = (xv.y-mean)*rstd*sv.y + bv.y;
  float o2 = (xv.z-mean)*rstd*sv.z + bv.z;
  float o3 = (xv.w-mean)*rstd*sv.w + bv.w;
  __hip_bfloat16* op = ob + (long)row*TC + c;
  *reinterpret_cast<__hip_bfloat162*>(op)   = __float22bfloat162_rn(make_float2(o0,o1));
  *reinterpret_cast<__hip_bfloat162*>(op+2) = __float22bfloat162_rn(make_float2(o2,o3));
}

// LN + gate logits fused (MoE); block 0 zeroes counts/psum; single barrier
// for the gate reduction (per-wave shuffle partials, cross-wave sum in LDS).
__global__ __launch_bounds__(256) void ln_gate_kernel(const float* __restrict__ x,
    const float* __restrict__ s, const float* __restrict__ b,
    __hip_bfloat16* __restrict__ ob, const float* __restrict__ gw,
    float* __restrict__ logits, int* __restrict__ counts, float* __restrict__ psum)
{
  int row = blockIdx.x, tid = threadIdx.x;
  if (row == 0 && tid < TE){ counts[tid] = 0; psum[tid] = 0.f; }
  const float* xr = x + (long)row*TC;
  int c = tid*4;
  float4 xv = *(const float4*)(xr + c);
  float sum = xv.x+xv.y+xv.z+xv.w;
  float sq = xv.x*xv.x+xv.y*xv.y+xv.z*xv.z+xv.w*xv.w;
  #pragma unroll
  for (int o=32;o;o>>=1){ sum += __shfl_down(sum,o); sq += __shfl_down(sq,o); }
  __shared__ float ls[8];
  if ((tid&63)==0){ ls[tid>>6] = sum; ls[4+(tid>>6)] = sq; }
  __syncthreads();
  float mean = (ls[0]+ls[1]+ls[2]+ls[3]) * (1.f/TC);
  float ex2  = (ls[4]+ls[5]+ls[6]+ls[7]) * (1.f/TC);
  float rstd = rsqrtf(ex2 - mean*mean + 1e-6f);
  float4 sv = *(const float4*)(s + c);
  float4 bv = *(const float4*)(b + c);
  float o0 = (xv.x-mean)*rstd*sv.x + bv.x;
  float o1 = (xv.y-mean)*rstd*sv.y + bv.y;
  float o2 = (xv.z-mean)*rstd*sv.z + bv.z;
  float o3 = (xv.w-mean)*rstd*sv.w + bv.w;
  __hip_bfloat16* op = ob + (long)row*TC + c;
  *reinterpret_cast<__hip_bfloat162*>(op)   = __float22bfloat162_rn(make_float2(o0,o1));
  *reinterpret_cast<__hip_bfloat162*>(op+2) = __float22bfloat162_rn(make_float2(o2,o3));
  // gate: per-wave partials for all 8 experts, ONE barrier, cross-wave sum
  __shared__ float gs[4][TE];
  int w = tid>>6;
  #pragma unroll
  for (int e=0;e<TE;e++){
    float4 wv = *(const float4*)(gw + (long)e*TC + c);
    float pr = o0*wv.x + o1*wv.y + o2*wv.z + o3*wv.w;
    #pragma unroll
    for (int o=32;o;o>>=1) pr += __shfl_down(pr,o);
    if ((tid&63)==0) gs[w][e] = pr;
  }
  __syncthreads();
  if (tid < TE)
    logits[(long)row*TE + tid] = gs[0][tid]+gs[1][tid]+gs[2][tid]+gs[3][tid];
}

// 10-block routing (r12-verified): global counts atomics, per-block psum.
__global__ __launch_bounds__(256) void routing_kernel(const float* __restrict__ logits,
    int* __restrict__ counts, int* __restrict__ etok,
    int* __restrict__ tEt, int* __restrict__ tPt, float* __restrict__ tGt,
    float* __restrict__ psum)
{
  __shared__ float ps[TE];
  int tid = threadIdx.x;
  if (tid < TE) ps[tid] = 0.f;
  __syncthreads();
  int t = blockIdx.x*256 + tid;
  if (t < TT){
    float pr[TE]; float mx = -3e38f;
    #pragma unroll
    for (int e=0;e<TE;e++){ pr[e] = logits[(long)t*TE+e]; mx = fmaxf(mx, pr[e]); }
    float sum = 0.f;
    #pragma unroll
    for (int e=0;e<TE;e++){ pr[e] = __expf(pr[e]-mx); sum += pr[e]; }
    float inv = 1.f/sum;
    #pragma unroll
    for (int e=0;e<TE;e++) pr[e] *= inv;
    int i1 = 0;
    #pragma unroll
    for (int e=1;e<TE;e++) if (pr[e] > pr[i1]) i1 = e;
    int i2 = -1;
    #pragma unroll
    for (int e=0;e<TE;e++){ if (e==i1) continue; if (i2<0 || pr[e]>pr[i2]) i2=e; }
    float p1 = pr[i1], p2 = pr[i2];
    float g1 = p1/(p1+p2), g2 = p2/(p1+p2);
    int pos1 = atomicAdd(&counts[i1], 1);
    etok[i1*TT + pos1] = t;
    int pos2 = atomicAdd(&counts[i2], 1);
    etok[i2*TT + pos2] = t;
    tEt[2*t] = i1; tPt[2*t] = pos1; tGt[2*t] = g1;
    tEt[2*t+1] = i2; tPt[2*t+1] = pos2; tGt[2*t+1] = g2;
    #pragma unroll
    for (int e=0;e<TE;e++) atomicAdd(&ps[e], pr[e]);
  }
  __syncthreads();
  if (tid < TE) atomicAdd(&psum[tid], ps[tid]);
}

__global__ void finalize_routing(const int* __restrict__ counts, int* __restrict__ offsets,
    const float* __restrict__ psum, float* __restrict__ aux,
    int* __restrict__ tE1, int* __restrict__ tL1, int* __restrict__ tC1, int* __restrict__ tO1,
    int* __restrict__ tE2, int* __restrict__ tL2, int* __restrict__ tC2, int* __restrict__ tO2)
{
  int off = 0; float a = 0.f; int n1 = 0, n2 = 0;
  for (int e=0;e<TE;e++){
    offsets[e] = off; int c = counts[e];
    for (int j=0;j<c;j+=256){ tE1[n1]=e; tL1[n1]=j; tC1[n1]=c; tO1[n1]=off; n1++; }
    for (int j=0;j<c;j+=128){ tE2[n2]=e; tL2[n2]=j; tC2[n2]=c; tO2[n2]=off; n2++; }
    a += (psum[e]*(1.f/TT)) * ((float)c*(1.f/TT));
    off += c;
  }
  for (;n1<NT1;n1++) tE1[n1] = -1;
  for (;n2<NT2;n2++) tE2[n2] = -1;
  aux[0] += (float)TE * a;
}

__global__ void build_qkv_bias(const float* __restrict__ qb, const float* __restrict__ vb,
    float* __restrict__ out)
{
  int i = blockIdx.x*256 + threadIdx.x;
  if (i >= 3*TC) return;
  float v = 0.f;
  if (i < TC) v = qb[i];
  else if (i >= 2*TC) v = vb[i-2*TC];
  out[i] = v;
}

// x[t] += (g1*(y0+y1)[s1] + g2*(y0+y1)[s2]) * gamma2; optional fused next-ln1.
__global__ __launch_bounds__(256) void combine_ln(
    const u16* __restrict__ y, long yck, const int* __restrict__ tEt,
    const int* __restrict__ tPt, const float* __restrict__ tGt,
    const int* __restrict__ offsets, const float* __restrict__ gamma2,
    float* __restrict__ x,
    const float* __restrict__ ln_s, const float* __restrict__ ln_b,
    __hip_bfloat16* __restrict__ ln_out)
{
  int t = blockIdx.x, tid = threadIdx.x, c = tid*4;
  int e1 = tEt[2*t], e2 = tEt[2*t+1];
  long s1 = (long)(offsets[e1]+tPt[2*t])*TC + c;
  long s2 = (long)(offsets[e2]+tPt[2*t+1])*TC + c;
  float g1 = tGt[2*t], g2 = tGt[2*t+1];
  ushort4 a0 = *(const ushort4*)(y+s1);
  ushort4 a1 = *(const ushort4*)(y+yck+s1);
  ushort4 b0 = *(const ushort4*)(y+s2);
  ushort4 b1 = *(const ushort4*)(y+yck+s2);
  float4 gv = *(const float4*)(gamma2 + c);
  float* xp = x + (long)t*TC + c;
  float4 xv = *(const float4*)xp;
  xv.x += (g1*(b2f_(a0.x)+b2f_(a1.x)) + g2*(b2f_(b0.x)+b2f_(b1.x)))*gv.x;
  xv.y += (g1*(b2f_(a0.y)+b2f_(a1.y)) + g2*(b2f_(b0.y)+b2f_(b1.y)))*gv.y;
  xv.z += (g1*(b2f_(a0.z)+b2f_(a1.z)) + g2*(b2f_(b0.z)+b2f_(b1.z)))*gv.z;
  xv.w += (g1*(b2f_(a0.w)+b2f_(a1.w)) + g2*(b2f_(b0.w)+b2f_(b1.w)))*gv.w;
  *(float4*)xp = xv;
  if (!ln_out) return;
  float sum = xv.x+xv.y+xv.z+xv.w;
  float sq = xv.x*xv.x+xv.y*xv.y+xv.z*xv.z+xv.w*xv.w;
  #pragma unroll
  for (int o=32;o;o>>=1){ sum += __shfl_down(sum,o); sq += __shfl_down(sq,o); }
  __shared__ float ls[8];
  if ((tid&63)==0){ ls[tid>>6] = sum; ls[4+(tid>>6)] = sq; }
  __syncthreads();
  float mean = (ls[0]+ls[1]+ls[2]+ls[3]) * (1.f/TC);
  float ex2  = (ls[4]+ls[5]+ls[6]+ls[7]) * (1.f/TC);
  float rstd = rsqrtf(ex2 - mean*mean + 1e-6f);
  float4 sv = *(const float4*)(ln_s + c);
  float4 bv = *(const float4*)(ln_b + c);
  float o0 = (xv.x-mean)*rstd*sv.x + bv.x;
  float o1 = (xv.y-mean)*rstd*sv.y + bv.y;
  float o2 = (xv.z-mean)*rstd*sv.z + bv.z;
  float o3 = (xv.w-mean)*rstd*sv.w + bv.w;
  __hip_bfloat16* op = ln_out + (long)t*TC + c;
  *reinterpret_cast<__hip_bfloat162*>(op)   = __float22bfloat162_rn(make_float2(o0,o1));
  *reinterpret_cast<__hip_bfloat162*>(op+2) = __float22bfloat162_rn(make_float2(o2,o3));
}

// ---------------------------------------------------------------------------
extern "C" void kernel_launch(void* const* d_in, const int* in_sizes, int n_in,
                              void* d_out, int out_size, void* d_ws, size_t ws_size,
                              hipStream_t stream) {
  (void)in_sizes; (void)n_in; (void)out_size; (void)ws_size;
  const float* hidden = (const float*)d_in[0];
  const int*   amask  = (const int*)d_in[1];
  const float* rpb    = (const float*)d_in[2];
  const float* qkv_w  = (const float*)d_in[3];
  const float* q_bias = (const float*)d_in[4];
  const float* v_bias = (const float*)d_in[5];
  const float* proj_w = (const float*)d_in[6];
  const float* proj_b = (const float*)d_in[7];
  const float* ln1_s  = (const float*)d_in[8];
  const float* ln1_b  = (const float*)d_in[9];
  const float* ln2_s  = (const float*)d_in[10];
  const float* ln2_b  = (const float*)d_in[11];
  const float* gamma1 = (const float*)d_in[12];
  const float* gamma2 = (const float*)d_in[13];
  const float* gate_w = (const float*)d_in[14];
  const float* fc1_w  = (const float*)d_in[15];
  const float* fc1_b  = (const float*)d_in[16];
  const float* fc2_w  = (const float*)d_in[17];
  const float* fc2_b  = (const float*)d_in[18];

  float* x = (float*)d_out;
  const int NXC = TT*TC;

  char* p = (char*)d_ws;
  auto alloc = [&](size_t bytes)->void* {
    void* r = (void*)p; p += (bytes + 255) & ~(size_t)255; return r;
  };
  float* qkvbias = (float*)alloc(3*TC*4);
  u16*   ln_bf   = (u16*)alloc((size_t)TT*TC*2);
  float* logits  = (float*)alloc((size_t)TT*TE*4);
  int*   counts  = (int*)alloc(TE*4);
  int*   offsets = (int*)alloc(TE*4);
  float* psum    = (float*)alloc(TE*4);
  int*   etok    = (int*)alloc((size_t)TE*TT*4);
  int*   tEt     = (int*)alloc((size_t)2*TT*4);
  int*   tPt     = (int*)alloc((size_t)2*TT*4);
  float* tGt     = (float*)alloc((size_t)2*TT*4);
  int*   tE1 = (int*)alloc(NT1*4); int* tL1 = (int*)alloc(NT1*4);
  int*   tC1 = (int*)alloc(NT1*4); int* tO1 = (int*)alloc(NT1*4);
  int*   tE2 = (int*)alloc(NT2*4); int* tL2 = (int*)alloc(NT2*4);
  int*   tC2 = (int*)alloc(NT2*4); int* tO2 = (int*)alloc(NT2*4);
  u16*   rpb16   = (u16*)alloc((size_t)TH*TN*TN*2);          // 13.1 MB
  char* arena = (char*)alloc(202375168);
  // attention phase (high region)
  u16*   qkv_bf  = (u16*)(arena + 157286400);               //  15,728,640
  u16*   vT      = (u16*)(arena + 183500800);               //   5,242,880
  u16*   attn_o  = (u16*)(arena + 188743680);               //   5,242,880
  u16*   wqkv    = (u16*)(arena + 193986560);               //   6,291,456
  u16*   wproj   = (u16*)(arena + 200278016);               //   2,097,152
  // MoE phase (overlays attention-phase low region — dead by then)
  u16*   fc1b    = (u16*)(arena);                           //  67,108,864
  u16*   fc2b    = (u16*)(arena + 67108864);                //  67,108,864
  u16*   h1      = (u16*)(arena + 134217728);               //  41,943,040 (5120 x TI bf16)
  u16*   yslot   = (u16*)(arena + 176160768);               //  20,971,520 (2 x 5120 x TC bf16)
  const long YCK = (long)5120*TC;

  init_x_kernel<<<(NXC+1+255)/256, 256, 0, stream>>>(hidden, x, NXC);
  cvt_kernel<<<(TH*TN*TN)/2048, 256, 0, stream>>>(rpb, rpb16, (long)TH*TN*TN);

  for (int l=0;l<2;l++){
    // --- attention ---
    if (l == 0)
      ln_kernel<<<TT, 256, 0, stream>>>(x, ln1_s, ln1_b, (__hip_bfloat16*)ln_bf);
    build_qkv_bias<<<(3*TC+255)/256, 256, 0, stream>>>(q_bias + l*TC, v_bias + l*TC, qkvbias);
    cvt2<<<(4*TC*TC)/2048, 256, 0, stream>>>(
        qkv_w + (size_t)l*3*TC*TC, wqkv, (long)3*TC*TC,
        proj_w + (size_t)l*TC*TC, wproj, (long)TC*TC);
    // qkv: 128x128 tiles, 480 blocks, 64KB LDS -> 2 blocks/CU
    gemm8<128,128,0,1><<<dim3(20*24,1,1), 512, 0, stream>>>(
        ln_bf, wqkv, qkv_bf, qkvbias, 0,
        nullptr, nullptr, nullptr, nullptr, nullptr,
        TT, TC, TC, 20, 3*TC, 0, 0);
    v_transpose<<<dim3(TN/128, TBH), 256, 0, stream>>>(qkv_bf, vT);
    // fattn: 64-row q-tiles, 640 blocks, ~49KB LDS
    fattn<<<dim3(TBH*10,1,1), 256, 0, stream>>>(qkv_bf, vT, rpb16, amask, attn_o);
    cvt2<<<(2*TE*TI*TC)/2048, 256, 0, stream>>>(
        fc1_w + (size_t)l*TE*TI*TC, fc1b, (long)TE*TI*TC,
        fc2_w + (size_t)l*TE*TC*TI, fc2b, (long)TE*TC*TI);
    gemm_bt<64,128,2><<<dim3(8*40,1,1), 256, 0, stream>>>(
        attn_o, wproj, x, proj_b + l*TC, gamma1 + l*TC,
        TT, TC, 40, TC);

    // --- MoE ---
    ln_gate_kernel<<<TT, 256, 0, stream>>>(x, ln2_s + l*TC, ln2_b + l*TC,
        (__hip_bfloat16*)ln_bf, gate_w + (size_t)l*TE*TC, logits, counts, psum);
    routing_kernel<<<(TT+255)/256, 256, 0, stream>>>(logits, counts, etok, tEt, tPt, tGt, psum);
    finalize_routing<<<1, 1, 0, stream>>>(counts, offsets, psum, x + NXC,
        tE1, tL1, tC1, tO1, tE2, tL2, tC2, tO2);
    // fc1: 128x128 tiles (64KB LDS -> 2 blocks/CU), gather, gelu
    gemm8<128,128,1,3><<<dim3(32*NT2,1,1), 512, 0, stream>>>(
        ln_bf, fc1b, h1, fc1_b + (size_t)l*TE*TI, TI,
        tE2, tL2, tC2, tO2, etok,
        0, TC, TC, 32, TI, (long)TI*TC, 0);
    // fc2: 128x128 tiles (64KB LDS -> 2 blocks/CU), compact rows, split-K=2
    gemm8<128,128,2,1><<<dim3(8*NT2,1,2), 512, 0, stream>>>(
        h1, fc2b, yslot, fc2_b + (size_t)l*TE*TC, TC,
        tE2, tL2, tC2, tO2, nullptr,
        0, TI, TI/2, 8, TC, (long)TC*TI, YCK);
    // combine + (for l=0) fused ln1 of next layer
    combine_ln<<<TT, 256, 0, stream>>>(yslot, YCK, tEt, tPt, tGt, offsets,
        gamma2 + l*TC, x,
        ln1_s + (l+1)*TC, ln1_b + (l+1)*TC,
        (l == 0) ? (__hip_bfloat16*)ln_bf : nullptr);
  }
}